// Round 12
// baseline (416.740 us; speedup 1.0000x reference)
//
#include <hip/hip_runtime.h>

// ---------------- problem constants ----------------
constexpr int B_ = 8, T_ = 256, H_ = 64, L_ = 3, NB_ = 17, NF_ = 68, HP_ = 6, K_ = 9;
constexpr int FEAT_DIM = NB_ * H_ + NF_ * H_ + H_;   // 5504
constexpr int HT = H_ * T_;                          // 16384 per (b,n)

typedef _Float16 half4_t __attribute__((ext_vector_type(4)));
typedef _Float16 half8_t __attribute__((ext_vector_type(8)));
typedef float f32x16 __attribute__((ext_vector_type(16)));
typedef float f32x4 __attribute__((ext_vector_type(4)));

// ---------------- workspace layout (float units); activations f16 [bn][o][T] ----------------
constexpr size_t SZ_AB = (size_t)B_ * NB_ * HT;
constexpr size_t SZ_AF = (size_t)B_ * NF_ * HT;
constexpr size_t OFF_TB   = 0;
constexpr size_t OFF_TF   = OFF_TB + SZ_AB / 2;
constexpr size_t OFF_SUPB = OFF_TF + SZ_AF / 2;
constexpr size_t OFF_SUPF = OFF_SUPB + SZ_AB / 2;
constexpr size_t OFF_GB   = OFF_SUPF + SZ_AF / 2;
constexpr size_t OFF_GF   = OFF_GB + SZ_AB / 2;
constexpr size_t OFF_W3   = OFF_GF + SZ_AF / 2;      // 4 conv sets x 110592 f16
constexpr size_t OFF_GW3  = OFF_W3 + 4 * 55296;      // 2 x 12288 f16
constexpr size_t OFF_B2   = OFF_GW3 + 2 * 6144;      // 4 x 192 f32
constexpr size_t OFF_ADJPB= OFF_B2 + 768;            // 32x32 f16
constexpr size_t OFF_ADJPF= OFF_ADJPB + 512;         // 96x80 f16
constexpr size_t OFF_FEAT = OFF_ADJPF + 3840;        // 8x5504 f32
constexpr size_t OFF_P1   = OFF_FEAT + (size_t)B_ * FEAT_DIM;

// ---------------- prep: fold BN into conv W -> f16 [l][tap][i8][o][j], 4 sets ----------------
struct ConvPrepSet { const float *w, *tb, *g, *bb, *m, *v; };

__global__ __launch_bounds__(256) void prep_convW_all(ConvPrepSet s0, ConvPrepSet s1,
                                                      ConvPrepSet s2, ConvPrepSet s3,
                                                      _Float16* __restrict__ w3,
                                                      float* __restrict__ b2) {
    int set = blockIdx.y;
    ConvPrepSet s = (set == 0) ? s0 : (set == 1) ? s1 : (set == 2) ? s2 : s3;
    int idx = blockIdx.x * 256 + threadIdx.x;           // < 110592
    int k = idx % K_; int r = idx / K_;
    int i = r % H_; r /= H_;
    int o = r % H_; int l = r / H_;
    float sc = s.g[l * H_ + o] * rsqrtf(s.v[l * H_ + o] + 1e-5f);
    w3[(size_t)set * 110592 + ((((l * K_ + k) * 8 + (i >> 3)) * H_ + o) * 8) + (i & 7)]
        = (_Float16)(s.w[idx] * sc);
    if (i == 0 && k == 0)
        b2[set * 192 + l * H_ + o] =
            s.tb[l * H_ + o] * sc + s.bb[l * H_ + o] - s.m[l * H_ + o] * sc;
}

__global__ __launch_bounds__(256) void prep_gcw_all(const float* __restrict__ g0,
                                                    const float* __restrict__ g1,
                                                    _Float16* __restrict__ w3) {
    int set = blockIdx.y;
    const float* gw = set ? g1 : g0;
    int idx = blockIdx.x * 256 + threadIdx.x;           // < 12288
    int o = idx % H_; int r = idx / H_;
    int c = r % H_; int l = r / H_;
    w3[(size_t)set * 12288 + (((l * 8 + (c >> 3)) * H_ + o) * 8) + (c & 7)] = (_Float16)gw[idx];
}

// padded f16 adj ([m][Kpad] A-layout) + zero p1 + zero feat
__global__ __launch_bounds__(256) void prep_misc(const float* __restrict__ adjB,
                                                 const float* __restrict__ adjF,
                                                 _Float16* __restrict__ pB,
                                                 _Float16* __restrict__ pF,
                                                 float* __restrict__ p1,
                                                 float* __restrict__ feat) {
    int idx = blockIdx.x * 256 + threadIdx.x;
    if (idx < 1024) {
        int m = idx >> 5, k = idx & 31;
        pB[idx] = (m < NB_ && k < NB_) ? (_Float16)adjB[m * NB_ + k] : (_Float16)0.f;
    } else if (idx < 8704) {
        int j = idx - 1024;
        int m = j / 80, k = j % 80;
        pF[j] = (m < NF_ && k < NF_) ? (_Float16)adjF[m * NF_ + k] : (_Float16)0.f;
    } else if (idx < 10752) {
        p1[idx - 8704] = 0.f;
    } else if (idx < 10752 + B_ * FEAT_DIM) {
        feat[idx - 10752] = 0.f;
    }
}

// ---------------- projection -> trunk f16 [bn][o][T] ; tail blocks do head stream ----------------
__global__ __launch_bounds__(256) void proj_kernel(const float* __restrict__ kpsB,
                                                   const float* __restrict__ pwB,
                                                   const float* __restrict__ pbB,
                                                   _Float16* __restrict__ outB,
                                                   const float* __restrict__ kpsF,
                                                   const float* __restrict__ pwF,
                                                   const float* __restrict__ pbF,
                                                   _Float16* __restrict__ outF,
                                                   const float* __restrict__ hx,
                                                   const float* __restrict__ hw,
                                                   const float* __restrict__ hb,
                                                   float* __restrict__ feat,
                                                   int nblk0, int nblk1) {
    int blk = blockIdx.x;
    if (blk >= nblk1) {             // head stream: 8 blocks, 64 lanes used
        int b = blk - nblk1;
        int c = threadIdx.x;
        if (c >= 64) return;
        float w0 = hw[c], w1 = hw[64 + c], w2 = hw[128 + c],
              w3 = hw[192 + c], w4 = hw[256 + c], w5 = hw[320 + c];
        float bias = hb[c];
        float acc = 0.f;
        for (int t = 0; t < T_; ++t) {
            const float* xr = hx + ((size_t)b * T_ + t) * HP_;
            float s = fmaf(xr[0], w0, fmaf(xr[1], w1, fmaf(xr[2], w2,
                      fmaf(xr[3], w3, fmaf(xr[4], w4, fmaf(xr[5], w5, bias))))));
            acc += fmaxf(s, 0.f);
        }
        feat[(size_t)b * FEAT_DIM + NB_ * H_ + NF_ * H_ + c] = acc * (1.f / 256.f);
        return;
    }
    const float *kps, *pw, *pb; _Float16* out; int N, bn;
    if (blk < nblk0) { kps = kpsB; pw = pwB; pb = pbB; out = outB; N = NB_; bn = blk; }
    else { kps = kpsF; pw = pwF; pb = pbF; out = outF; N = NF_; bn = blk - nblk0; }
    int b = bn / N, n = bn % N;
    int t = threadIdx.x;
    float x0 = kps[((size_t)b * T_ + t) * (N * 2) + n * 2 + 0];
    float x1 = kps[((size_t)b * T_ + t) * (N * 2) + n * 2 + 1];
    _Float16* ob = out + (size_t)bn * HT + t;
#pragma unroll 8
    for (int c = 0; c < H_; ++c)
        ob[(size_t)c * T_] = (_Float16)fmaf(x0, pw[c], fmaf(x1, pw[H_ + c], pb[c]));
}

__device__ __forceinline__ half8_t ld_b8(const _Float16* p) {
    half4_t lo = *(const half4_t*)p;
    half4_t hi = *(const half4_t*)(p + 4);
    return __builtin_shufflevector(lo, hi, 0, 1, 2, 3, 4, 5, 6, 7);
}

// stage f16 [c][T] -> Xs[t_local+4][c], pitch 68 (gather: 8 coalesced u16 loads -> 2 b64 writes)
__device__ __forceinline__ void stage_f16(const _Float16* __restrict__ xb,
                                          _Float16* __restrict__ Xs, int tc, int tid, int step) {
    for (int u = tid; u < 8 * 136; u += step) {
        int oct = u / 136;
        int row = u - oct * 136;
        int t = tc * 128 + row - 4;
        _Float16 v[8];
        if (t >= 0 && t < T_) {
            const _Float16* xr = xb + (size_t)(oct * 8) * T_ + t;
#pragma unroll
            for (int j = 0; j < 8; ++j) v[j] = xr[(size_t)j * T_];
        } else {
#pragma unroll
            for (int j = 0; j < 8; ++j) v[j] = (_Float16)0.f;
        }
        _Float16* dst = &Xs[row * 68 + oct * 8];
        half4_t lo, hi;
#pragma unroll
        for (int j = 0; j < 4; ++j) { lo[j] = v[j]; hi[j] = v[4 + j]; }
        *(half4_t*)dst = lo;
        *(half4_t*)(dst + 4) = hi;
    }
}

// ---------------- fused conv1(+bn+relu)+channel-mix : trunk f16 -> support f16 ----------------
// block = (bn, t-chunk 128), 128 thr / 2 waves; wave w: t-slab w*64 (2 t-tiles), BOTH o-tiles.
// Per K-step: 2 A loads + 2 B LDS reads feed 4 MFMA (B and A each reused 2x -> 512 B LDS/MFMA).
struct CM {
    const _Float16* x; const half8_t* w1; const float* b1; const half8_t* gc; _Float16* sup;
};

__global__ __launch_bounds__(128) void convmix_kernel(CM P0, CM P1, int nblk0, int l) {
    __shared__ __align__(16) _Float16 Xs[136 * 68];
    int blk = blockIdx.x;
    CM P = (blk < nblk0) ? P0 : P1;
    if (blk >= nblk0) blk -= nblk0;
    int bn = blk >> 1, tc = blk & 1;
    int tid = threadIdx.x;
    stage_f16(P.x + (size_t)bn * HT, Xs, tc, tid, 128);
    __syncthreads();

    int ln = tid & 63;
    int w = __builtin_amdgcn_readfirstlane(tid >> 6);   // 0..1
    int ln31 = ln & 31, kg = ln >> 5;
    int tsub = w * 64;

    f32x16 acc[2][2];   // [mt][ts]
#pragma unroll
    for (int mt = 0; mt < 2; ++mt)
#pragma unroll
        for (int ts = 0; ts < 2; ++ts)
#pragma unroll
            for (int r = 0; r < 16; ++r) acc[mt][ts][r] = 0.f;

    const half8_t* wl = P.w1 + (size_t)l * (K_ * 8 * H_);
#pragma unroll
    for (int tap = 0; tap < K_; ++tap) {
#pragma unroll
        for (int ks = 0; ks < 4; ++ks) {
            int i8 = ks * 2 + kg;
            half8_t a0 = wl[(tap * 8 + i8) * H_ + ln31];
            half8_t a1 = wl[(tap * 8 + i8) * H_ + 32 + ln31];
#pragma unroll
            for (int ts = 0; ts < 2; ++ts) {
                half8_t bf = ld_b8(&Xs[(tsub + ts * 32 + ln31 + tap) * 68 + i8 * 8]);
                acc[0][ts] = __builtin_amdgcn_mfma_f32_32x32x16_f16(a0, bf, acc[0][ts], 0, 0, 0);
                acc[1][ts] = __builtin_amdgcn_mfma_f32_32x32x16_f16(a1, bf, acc[1][ts], 0, 0, 0);
            }
        }
    }
    __syncthreads();

    // conv1 epilogue: bias+relu -> mid rows Xs[4+t][o]
#pragma unroll
    for (int ts = 0; ts < 2; ++ts) {
        int row = 4 + tsub + ts * 32 + ln31;
#pragma unroll
        for (int mt = 0; mt < 2; ++mt) {
#pragma unroll
            for (int rg = 0; rg < 4; ++rg) {
                int o0 = mt * 32 + rg * 8 + kg * 4;
                f32x4 bv = *(const f32x4*)(P.b1 + l * H_ + o0);
                half4_t hv;
#pragma unroll
                for (int j = 0; j < 4; ++j)
                    hv[j] = (_Float16)fmaxf(acc[mt][ts][rg * 4 + j] + bv[j], 0.f);
                *(half4_t*)(&Xs[row * 68 + o0]) = hv;
            }
        }
    }
    __syncthreads();

    // channel mix (K=64)
    f32x16 acc2[2][2];
#pragma unroll
    for (int mt = 0; mt < 2; ++mt)
#pragma unroll
        for (int ts = 0; ts < 2; ++ts)
#pragma unroll
            for (int r = 0; r < 16; ++r) acc2[mt][ts][r] = 0.f;
    const half8_t* gl = P.gc + (size_t)l * (8 * H_);
#pragma unroll
    for (int ks = 0; ks < 4; ++ks) {
        int i8 = ks * 2 + kg;
        half8_t a0 = gl[i8 * H_ + ln31];
        half8_t a1 = gl[i8 * H_ + 32 + ln31];
#pragma unroll
        for (int ts = 0; ts < 2; ++ts) {
            half8_t bf = ld_b8(&Xs[(4 + tsub + ts * 32 + ln31) * 68 + i8 * 8]);
            acc2[0][ts] = __builtin_amdgcn_mfma_f32_32x32x16_f16(a0, bf, acc2[0][ts], 0, 0, 0);
            acc2[1][ts] = __builtin_amdgcn_mfma_f32_32x32x16_f16(a1, bf, acc2[1][ts], 0, 0, 0);
        }
    }

    // store support f16 [bn][o][T]
    _Float16* sp = P.sup + (size_t)bn * HT + tc * 128;
#pragma unroll
    for (int mt = 0; mt < 2; ++mt) {
#pragma unroll
        for (int ts = 0; ts < 2; ++ts) {
            int t = tsub + ts * 32 + ln31;
#pragma unroll
            for (int r = 0; r < 16; ++r) {
                int o = mt * 32 + (r & 3) + 8 * (r >> 2) + 4 * kg;
                sp[(size_t)o * T_ + t] = (_Float16)acc2[mt][ts][r];
            }
        }
    }
}

// ---------------- conv2(+bn)+residual : G f16 -> trunk f16; LAST: mean-pool -> feat ----------------
struct C2 {
    const _Float16* x; const half8_t* w2; const float* b2; _Float16* trunk; int N; int fbase;
};

template <bool LAST>
__global__ __launch_bounds__(128) void conv2_kernel(C2 P0, C2 P1, int nblk0, int l,
                                                    float* __restrict__ feat) {
    __shared__ __align__(16) _Float16 Xs[136 * 68];
    int blk = blockIdx.x;
    C2 P = (blk < nblk0) ? P0 : P1;
    if (blk >= nblk0) blk -= nblk0;
    int bn = blk >> 1, tc = blk & 1;
    int tid = threadIdx.x;
    stage_f16(P.x + (size_t)bn * HT, Xs, tc, tid, 128);
    __syncthreads();

    int ln = tid & 63;
    int w = __builtin_amdgcn_readfirstlane(tid >> 6);   // 0..1
    int ln31 = ln & 31, kg = ln >> 5;
    int tsub = w * 64;

    f32x16 acc[2][2];
#pragma unroll
    for (int mt = 0; mt < 2; ++mt)
#pragma unroll
        for (int ts = 0; ts < 2; ++ts)
#pragma unroll
            for (int r = 0; r < 16; ++r) acc[mt][ts][r] = 0.f;

    const half8_t* wl = P.w2 + (size_t)l * (K_ * 8 * H_);
#pragma unroll
    for (int tap = 0; tap < K_; ++tap) {
#pragma unroll
        for (int ks = 0; ks < 4; ++ks) {
            int i8 = ks * 2 + kg;
            half8_t a0 = wl[(tap * 8 + i8) * H_ + ln31];
            half8_t a1 = wl[(tap * 8 + i8) * H_ + 32 + ln31];
#pragma unroll
            for (int ts = 0; ts < 2; ++ts) {
                half8_t bf = ld_b8(&Xs[(tsub + ts * 32 + ln31 + tap) * 68 + i8 * 8]);
                acc[0][ts] = __builtin_amdgcn_mfma_f32_32x32x16_f16(a0, bf, acc[0][ts], 0, 0, 0);
                acc[1][ts] = __builtin_amdgcn_mfma_f32_32x32x16_f16(a1, bf, acc[1][ts], 0, 0, 0);
            }
        }
    }

    const _Float16* resb = P.trunk + (size_t)bn * HT + tc * 128;
    if (!LAST) {
        _Float16* tob = P.trunk + (size_t)bn * HT + tc * 128;
#pragma unroll
        for (int mt = 0; mt < 2; ++mt) {
#pragma unroll
            for (int ts = 0; ts < 2; ++ts) {
                int t = tsub + ts * 32 + ln31;
#pragma unroll
                for (int r = 0; r < 16; ++r) {
                    int o = mt * 32 + (r & 3) + 8 * (r >> 2) + 4 * kg;
                    float y = acc[mt][ts][r] + P.b2[l * H_ + o] + (float)resb[(size_t)o * T_ + t];
                    tob[(size_t)o * T_ + t] = (_Float16)y;
                }
            }
        }
    } else {
        __syncthreads();   // Xs reads done; reuse as reduction scratch
        float* red = (float*)Xs;
        float sv[2][16];
#pragma unroll
        for (int mt = 0; mt < 2; ++mt) {
#pragma unroll
            for (int r = 0; r < 16; ++r) {
                int o = mt * 32 + (r & 3) + 8 * (r >> 2) + 4 * kg;
                float bias = P.b2[l * H_ + o];
                float s = acc[mt][0][r] + bias + (float)resb[(size_t)o * T_ + tsub + ln31]
                        + acc[mt][1][r] + bias + (float)resb[(size_t)o * T_ + tsub + 32 + ln31];
#pragma unroll
                for (int off = 1; off < 32; off <<= 1) s += __shfl_xor(s, off);
                sv[mt][r] = s;
            }
        }
        if (ln31 == 0) {
#pragma unroll
            for (int mt = 0; mt < 2; ++mt)
#pragma unroll
                for (int r = 0; r < 16; ++r) {
                    int o = mt * 32 + (r & 3) + 8 * (r >> 2) + 4 * kg;
                    red[w * 64 + o] = sv[mt][r];
                }
        }
        __syncthreads();
        if (tid < 64) {
            float s = red[tid] + red[64 + tid];
            int b = bn / P.N, n = bn % P.N;
            atomicAdd(&feat[(size_t)b * FEAT_DIM + P.fbase + n * H_ + tid], s * (1.f / 256.f));
        }
    }
}

// ---------------- adjmix MFMA: out = relu(adj @ sup + gb) ----------------
template <int N, int MT, int KS>
__device__ __forceinline__ void adjmix_impl(const _Float16* __restrict__ sup,
                                            const half8_t* __restrict__ adjP,
                                            const float* __restrict__ gb,
                                            _Float16* __restrict__ out,
                                            int blk, int l, _Float16* Ls, int tid) {
    constexpr int KP = KS * 16;
    constexpr int PITCH = KP + 4;
    int b = blk >> 7, cb = blk & 127;
    int colbase = cb * 128;
    float gbv = gb[l * H_ + (cb >> 1)];

    for (int u = tid; u < KP * 16; u += 256) {
        int n = u >> 4, cs = u & 15;
        half8_t v;
        if (n < N) v = *(const half8_t*)(sup + (size_t)(b * N + n) * HT + colbase + cs * 8);
        else {
#pragma unroll
            for (int j = 0; j < 8; ++j) v[j] = (_Float16)0.f;
        }
#pragma unroll
        for (int j = 0; j < 8; ++j) Ls[(cs * 8 + j) * PITCH + n] = v[j];
    }
    __syncthreads();

    int ln = tid & 63;
    int w = __builtin_amdgcn_readfirstlane(tid >> 6);
    int ln31 = ln & 31, kg = ln >> 5;
    int colL = w * 32 + ln31;

    f32x16 acc[MT];
#pragma unroll
    for (int mt = 0; mt < MT; ++mt)
#pragma unroll
        for (int r = 0; r < 16; ++r) acc[mt][r] = 0.f;

#pragma unroll
    for (int ks = 0; ks < KS; ++ks) {
        half8_t bf = ld_b8(&Ls[colL * PITCH + ks * 16 + kg * 8]);
#pragma unroll
        for (int mt = 0; mt < MT; ++mt) {
            half8_t af = adjP[(size_t)(mt * 32 + ln31) * (KP / 8) + ks * 2 + kg];
            acc[mt] = __builtin_amdgcn_mfma_f32_32x32x16_f16(af, bf, acc[mt], 0, 0, 0);
        }
    }

    int col = colbase + colL;
#pragma unroll
    for (int mt = 0; mt < MT; ++mt) {
#pragma unroll
        for (int r = 0; r < 16; ++r) {
            int m = mt * 32 + (r & 3) + 8 * (r >> 2) + 4 * kg;
            if (m < N)
                out[(size_t)(b * N + m) * HT + col] = (_Float16)fmaxf(acc[mt][r] + gbv, 0.f);
        }
    }
}

__global__ __launch_bounds__(256) void adjmix_kernel(
        const _Float16* __restrict__ supB, const half8_t* __restrict__ adjPB,
        const float* __restrict__ gbB, _Float16* __restrict__ outB,
        const _Float16* __restrict__ supF, const half8_t* __restrict__ adjPF,
        const float* __restrict__ gbF, _Float16* __restrict__ outF,
        int nblk0, int l) {
    __shared__ __align__(16) _Float16 Ls[128 * 84];
    int blk = blockIdx.x, tid = threadIdx.x;
    if (blk < nblk0)
        adjmix_impl<NB_, 1, 2>(supB, adjPB, gbB, outB, blk, l, Ls, tid);
    else
        adjmix_impl<NF_, 3, 5>(supF, adjPF, gbF, outF, blk - nblk0, l, Ls, tid);
}

// ---------------- fusion layer 1 (5504 -> 256), split-K ----------------
__global__ __launch_bounds__(256) void fus1_kernel(const float* __restrict__ feat,
                                                   const float* __restrict__ w1,
                                                   float* __restrict__ p1) {
    __shared__ float fv[128];
    int b = blockIdx.x / 43, ic = blockIdx.x % 43;
    int tid = threadIdx.x;
    if (tid < 128) fv[tid] = feat[(size_t)b * FEAT_DIM + ic * 128 + tid];
    __syncthreads();
    const float* wb = w1 + (size_t)(ic * 128) * 256 + tid;
    float acc = 0.f;
#pragma unroll 4
    for (int i = 0; i < 128; ++i)
        acc = fmaf(fv[i], wb[(size_t)i * 256], acc);
    atomicAdd(&p1[b * 256 + tid], acc);
}

// ---------------- fusion tail ----------------
__global__ __launch_bounds__(256) void fus_tail_kernel(const float* __restrict__ p1,
        const float* __restrict__ b1, const float* __restrict__ w2, const float* __restrict__ b2,
        const float* __restrict__ w3, const float* __restrict__ b3,
        const float* __restrict__ w4, const float* __restrict__ b4, float* __restrict__ out) {
    __shared__ float s1[256], s2[128], s3[64];
    int b = blockIdx.x, tid = threadIdx.x;
    s1[tid] = fmaxf(p1[b * 256 + tid] + b1[tid], 0.f);
    __syncthreads();
    if (tid < 128) {
        float acc = b2[tid];
        for (int i = 0; i < 256; ++i) acc = fmaf(s1[i], w2[i * 128 + tid], acc);
        s2[tid] = fmaxf(acc, 0.f);
    }
    __syncthreads();
    if (tid < 64) {
        float acc = b3[tid];
        for (int i = 0; i < 128; ++i) acc = fmaf(s2[i], w3[i * 64 + tid], acc);
        s3[tid] = fmaxf(acc, 0.f);
    }
    __syncthreads();
    if (tid < 5) {
        float acc = b4[tid];
        for (int i = 0; i < 64; ++i) acc = fmaf(s3[i], w4[i * 5 + tid], acc);
        out[b * 5 + tid] = acc;
    }
}

// ---------------- launch ----------------
extern "C" void kernel_launch(void* const* d_in, const int* in_sizes, int n_in,
                              void* d_out, int out_size, void* d_ws, size_t ws_size,
                              hipStream_t stream) {
    const float* body_kps = (const float*)d_in[0];
    const float* face_kps = (const float*)d_in[1];
    const float* head_pose = (const float*)d_in[2];
    const float* body_adj = (const float*)d_in[3];
    const float* face_adj = (const float*)d_in[4];
    const float* body_pw = (const float*)d_in[5];
    const float* body_pb = (const float*)d_in[6];
    const float* face_pw = (const float*)d_in[7];
    const float* face_pb = (const float*)d_in[8];
    const float* head_w = (const float*)d_in[9];
    const float* head_b = (const float*)d_in[10];
    const float* b_t1w = (const float*)d_in[11]; const float* b_t1b = (const float*)d_in[12];
    const float* b_g1  = (const float*)d_in[13]; const float* b_b1  = (const float*)d_in[14];
    const float* b_m1  = (const float*)d_in[15]; const float* b_v1  = (const float*)d_in[16];
    const float* b_gcw = (const float*)d_in[17]; const float* b_gcb = (const float*)d_in[18];
    const float* b_t2w = (const float*)d_in[19]; const float* b_t2b = (const float*)d_in[20];
    const float* b_g2  = (const float*)d_in[21]; const float* b_b2  = (const float*)d_in[22];
    const float* b_m2  = (const float*)d_in[23]; const float* b_v2  = (const float*)d_in[24];
    const float* f_t1w = (const float*)d_in[25]; const float* f_t1b = (const float*)d_in[26];
    const float* f_g1  = (const float*)d_in[27]; const float* f_b1  = (const float*)d_in[28];
    const float* f_m1  = (const float*)d_in[29]; const float* f_v1  = (const float*)d_in[30];
    const float* f_gcw = (const float*)d_in[31]; const float* f_gcb = (const float*)d_in[32];
    const float* f_t2w = (const float*)d_in[33]; const float* f_t2b = (const float*)d_in[34];
    const float* f_g2  = (const float*)d_in[35]; const float* f_b2  = (const float*)d_in[36];
    const float* f_m2  = (const float*)d_in[37]; const float* f_v2  = (const float*)d_in[38];
    const float* fus1_w = (const float*)d_in[39]; const float* fus1_b = (const float*)d_in[40];
    const float* fus2_w = (const float*)d_in[41]; const float* fus2_b = (const float*)d_in[42];
    const float* fus3_w = (const float*)d_in[43]; const float* fus3_b = (const float*)d_in[44];
    const float* fus4_w = (const float*)d_in[45]; const float* fus4_b = (const float*)d_in[46];

    float* ws = (float*)d_ws;
    _Float16* TrB = (_Float16*)(ws + OFF_TB);
    _Float16* TrF = (_Float16*)(ws + OFF_TF);
    _Float16* SupB = (_Float16*)(ws + OFF_SUPB);
    _Float16* SupF = (_Float16*)(ws + OFF_SUPF);
    _Float16* Gb = (_Float16*)(ws + OFF_GB);
    _Float16* Gf = (_Float16*)(ws + OFF_GF);
    _Float16* W3 = (_Float16*)(ws + OFF_W3);
    _Float16* W3b1 = W3;            _Float16* W3b2 = W3 + 110592;
    _Float16* W3f1 = W3 + 221184;   _Float16* W3f2 = W3 + 331776;
    _Float16* GW3 = (_Float16*)(ws + OFF_GW3);
    _Float16* GW3b = GW3;           _Float16* GW3f = GW3 + 12288;
    float* B2 = ws + OFF_B2;
    float* B2b1 = B2;        float* B2b2 = B2 + 192;
    float* B2f1 = B2 + 384;  float* B2f2 = B2 + 576;
    _Float16* adjPB = (_Float16*)(ws + OFF_ADJPB);
    _Float16* adjPF = (_Float16*)(ws + OFF_ADJPF);
    float* feat = ws + OFF_FEAT;
    float* p1 = ws + OFF_P1;
    float* out = (float*)d_out;

    // prep
    ConvPrepSet sb1{b_t1w, b_t1b, b_g1, b_b1, b_m1, b_v1};
    ConvPrepSet sb2{b_t2w, b_t2b, b_g2, b_b2, b_m2, b_v2};
    ConvPrepSet sf1{f_t1w, f_t1b, f_g1, f_b1, f_m1, f_v1};
    ConvPrepSet sf2{f_t2w, f_t2b, f_g2, f_b2, f_m2, f_v2};
    prep_convW_all<<<dim3(432, 4), 256, 0, stream>>>(sb1, sb2, sf1, sf2, W3, B2);
    prep_gcw_all<<<dim3(48, 2), 256, 0, stream>>>(b_gcw, f_gcw, GW3);
    prep_misc<<<214, 256, 0, stream>>>(body_adj, face_adj, adjPB, adjPF, p1, feat);

    const int nB = B_ * NB_;   // 136
    const int nF = B_ * NF_;   // 544
    proj_kernel<<<nB + nF + B_, 256, 0, stream>>>(body_kps, body_pw, body_pb, TrB,
                                                  face_kps, face_pw, face_pb, TrF,
                                                  head_pose, head_w, head_b, feat,
                                                  nB, nB + nF);

    CM cmb{TrB, (const half8_t*)W3b1, B2b1, (const half8_t*)GW3b, SupB};
    CM cmf{TrF, (const half8_t*)W3f1, B2f1, (const half8_t*)GW3f, SupF};
    C2 c2b{Gb, (const half8_t*)W3b2, B2b2, TrB, NB_, 0};
    C2 c2f{Gf, (const half8_t*)W3f2, B2f2, TrF, NF_, NB_ * H_};

    const int gc = (nB + nF) * 2;   // 1360 blocks (128 threads each)
    const int n0 = nB * 2;          // 272
    const int ga = B_ * 128;        // 1024 per stream

    for (int l = 0; l < L_; ++l) {
        convmix_kernel<<<gc, 128, 0, stream>>>(cmb, cmf, n0, l);
        adjmix_kernel<<<2 * ga, 256, 0, stream>>>(SupB, (const half8_t*)adjPB, b_gcb, Gb,
                                                  SupF, (const half8_t*)adjPF, f_gcb, Gf, ga, l);
        if (l < L_ - 1)
            conv2_kernel<false><<<gc, 128, 0, stream>>>(c2b, c2f, n0, l, feat);
        else
            conv2_kernel<true><<<gc, 128, 0, stream>>>(c2b, c2f, n0, l, feat);
    }

    fus1_kernel<<<B_ * 43, 256, 0, stream>>>(feat, fus1_w, p1);
    fus_tail_kernel<<<B_, 256, 0, stream>>>(p1, fus1_b, fus2_w, fus2_b, fus3_w, fus3_b,
                                            fus4_w, fus4_b, out);
}

// Round 13
// 402.065 us; speedup vs baseline: 1.0365x; 1.0365x over previous
//
#include <hip/hip_runtime.h>

// ---------------- problem constants ----------------
constexpr int B_ = 8, T_ = 256, H_ = 64, L_ = 3, NB_ = 17, NF_ = 68, HP_ = 6, K_ = 9;
constexpr int FEAT_DIM = NB_ * H_ + NF_ * H_ + H_;   // 5504
constexpr int HT = H_ * T_;                          // 16384 per (b,n)

typedef _Float16 half4_t __attribute__((ext_vector_type(4)));
typedef _Float16 half8_t __attribute__((ext_vector_type(8)));
typedef float f32x16 __attribute__((ext_vector_type(16)));
typedef float f32x4 __attribute__((ext_vector_type(4)));

// ---------------- workspace layout (float units); activations f16 [bn][o][T] ----------------
constexpr size_t SZ_AB = (size_t)B_ * NB_ * HT;
constexpr size_t SZ_AF = (size_t)B_ * NF_ * HT;
constexpr size_t OFF_TB   = 0;
constexpr size_t OFF_TF   = OFF_TB + SZ_AB / 2;
constexpr size_t OFF_SUPB = OFF_TF + SZ_AF / 2;
constexpr size_t OFF_SUPF = OFF_SUPB + SZ_AB / 2;
constexpr size_t OFF_GB   = OFF_SUPF + SZ_AF / 2;
constexpr size_t OFF_GF   = OFF_GB + SZ_AB / 2;
constexpr size_t OFF_W3   = OFF_GF + SZ_AF / 2;      // 4 conv sets x 110592 f16
constexpr size_t OFF_GW3  = OFF_W3 + 4 * 55296;      // 2 x 12288 f16
constexpr size_t OFF_B2   = OFF_GW3 + 2 * 6144;      // 4 x 192 f32
constexpr size_t OFF_ADJPB= OFF_B2 + 768;            // 32x32 f16
constexpr size_t OFF_ADJPF= OFF_ADJPB + 512;         // 96x80 f16
constexpr size_t OFF_FEAT = OFF_ADJPF + 3840;        // 8x5504 f32
constexpr size_t OFF_P1   = OFF_FEAT + (size_t)B_ * FEAT_DIM;

// ---------------- prep: fold BN into conv W -> f16 [l][tap][i8][o][j], 4 sets ----------------
struct ConvPrepSet { const float *w, *tb, *g, *bb, *m, *v; };

__global__ __launch_bounds__(256) void prep_convW_all(ConvPrepSet s0, ConvPrepSet s1,
                                                      ConvPrepSet s2, ConvPrepSet s3,
                                                      _Float16* __restrict__ w3,
                                                      float* __restrict__ b2) {
    int set = blockIdx.y;
    ConvPrepSet s = (set == 0) ? s0 : (set == 1) ? s1 : (set == 2) ? s2 : s3;
    int idx = blockIdx.x * 256 + threadIdx.x;           // < 110592
    int k = idx % K_; int r = idx / K_;
    int i = r % H_; r /= H_;
    int o = r % H_; int l = r / H_;
    float sc = s.g[l * H_ + o] * rsqrtf(s.v[l * H_ + o] + 1e-5f);
    w3[(size_t)set * 110592 + ((((l * K_ + k) * 8 + (i >> 3)) * H_ + o) * 8) + (i & 7)]
        = (_Float16)(s.w[idx] * sc);
    if (i == 0 && k == 0)
        b2[set * 192 + l * H_ + o] =
            s.tb[l * H_ + o] * sc + s.bb[l * H_ + o] - s.m[l * H_ + o] * sc;
}

__global__ __launch_bounds__(256) void prep_gcw_all(const float* __restrict__ g0,
                                                    const float* __restrict__ g1,
                                                    _Float16* __restrict__ w3) {
    int set = blockIdx.y;
    const float* gw = set ? g1 : g0;
    int idx = blockIdx.x * 256 + threadIdx.x;           // < 12288
    int o = idx % H_; int r = idx / H_;
    int c = r % H_; int l = r / H_;
    w3[(size_t)set * 12288 + (((l * 8 + (c >> 3)) * H_ + o) * 8) + (c & 7)] = (_Float16)gw[idx];
}

// padded f16 adj ([m][Kpad] A-layout) + zero p1 + zero feat
__global__ __launch_bounds__(256) void prep_misc(const float* __restrict__ adjB,
                                                 const float* __restrict__ adjF,
                                                 _Float16* __restrict__ pB,
                                                 _Float16* __restrict__ pF,
                                                 float* __restrict__ p1,
                                                 float* __restrict__ feat) {
    int idx = blockIdx.x * 256 + threadIdx.x;
    if (idx < 1024) {
        int m = idx >> 5, k = idx & 31;
        pB[idx] = (m < NB_ && k < NB_) ? (_Float16)adjB[m * NB_ + k] : (_Float16)0.f;
    } else if (idx < 8704) {
        int j = idx - 1024;
        int m = j / 80, k = j % 80;
        pF[j] = (m < NF_ && k < NF_) ? (_Float16)adjF[m * NF_ + k] : (_Float16)0.f;
    } else if (idx < 10752) {
        p1[idx - 8704] = 0.f;
    } else if (idx < 10752 + B_ * FEAT_DIM) {
        feat[idx - 10752] = 0.f;
    }
}

// ---------------- projection -> trunk f16 [bn][o][T] ; tail blocks do head stream ----------------
__global__ __launch_bounds__(256) void proj_kernel(const float* __restrict__ kpsB,
                                                   const float* __restrict__ pwB,
                                                   const float* __restrict__ pbB,
                                                   _Float16* __restrict__ outB,
                                                   const float* __restrict__ kpsF,
                                                   const float* __restrict__ pwF,
                                                   const float* __restrict__ pbF,
                                                   _Float16* __restrict__ outF,
                                                   const float* __restrict__ hx,
                                                   const float* __restrict__ hw,
                                                   const float* __restrict__ hb,
                                                   float* __restrict__ feat,
                                                   int nblk0, int nblk1) {
    int blk = blockIdx.x;
    if (blk >= nblk1) {             // head stream: 8 blocks, 64 lanes used
        int b = blk - nblk1;
        int c = threadIdx.x;
        if (c >= 64) return;
        float w0 = hw[c], w1 = hw[64 + c], w2 = hw[128 + c],
              w3 = hw[192 + c], w4 = hw[256 + c], w5 = hw[320 + c];
        float bias = hb[c];
        float acc = 0.f;
        for (int t = 0; t < T_; ++t) {
            const float* xr = hx + ((size_t)b * T_ + t) * HP_;
            float s = fmaf(xr[0], w0, fmaf(xr[1], w1, fmaf(xr[2], w2,
                      fmaf(xr[3], w3, fmaf(xr[4], w4, fmaf(xr[5], w5, bias))))));
            acc += fmaxf(s, 0.f);
        }
        feat[(size_t)b * FEAT_DIM + NB_ * H_ + NF_ * H_ + c] = acc * (1.f / 256.f);
        return;
    }
    const float *kps, *pw, *pb; _Float16* out; int N, bn;
    if (blk < nblk0) { kps = kpsB; pw = pwB; pb = pbB; out = outB; N = NB_; bn = blk; }
    else { kps = kpsF; pw = pwF; pb = pbF; out = outF; N = NF_; bn = blk - nblk0; }
    int b = bn / N, n = bn % N;
    int t = threadIdx.x;
    float x0 = kps[((size_t)b * T_ + t) * (N * 2) + n * 2 + 0];
    float x1 = kps[((size_t)b * T_ + t) * (N * 2) + n * 2 + 1];
    _Float16* ob = out + (size_t)bn * HT + t;
#pragma unroll 8
    for (int c = 0; c < H_; ++c)
        ob[(size_t)c * T_] = (_Float16)fmaf(x0, pw[c], fmaf(x1, pw[H_ + c], pb[c]));
}

__device__ __forceinline__ half8_t ld_b8(const _Float16* p) {
    half4_t lo = *(const half4_t*)p;
    half4_t hi = *(const half4_t*)(p + 4);
    return __builtin_shufflevector(lo, hi, 0, 1, 2, 3, 4, 5, 6, 7);
}

// stage f16 [c][T] -> Xs[t_local+4][c], pitch 68 (gather: 8 coalesced u16 loads -> 2 b64 writes)
__device__ __forceinline__ void stage_f16(const _Float16* __restrict__ xb,
                                          _Float16* __restrict__ Xs, int tc, int tid) {
    for (int u = tid; u < 8 * 136; u += 256) {
        int oct = u / 136;
        int row = u - oct * 136;
        int t = tc * 128 + row - 4;
        _Float16 v[8];
        if (t >= 0 && t < T_) {
            const _Float16* xr = xb + (size_t)(oct * 8) * T_ + t;
#pragma unroll
            for (int j = 0; j < 8; ++j) v[j] = xr[(size_t)j * T_];
        } else {
#pragma unroll
            for (int j = 0; j < 8; ++j) v[j] = (_Float16)0.f;
        }
        _Float16* dst = &Xs[row * 68 + oct * 8];
        half4_t lo, hi;
#pragma unroll
        for (int j = 0; j < 4; ++j) { lo[j] = v[j]; hi[j] = v[4 + j]; }
        *(half4_t*)dst = lo;
        *(half4_t*)(dst + 4) = hi;
    }
}

// ---------------- fused conv1(+bn+relu)+channel-mix : trunk f16 -> support f16 ----------------
// block = (bn, t-chunk 128), 4 waves; wave w: o-tile (w&1)*32, t-slab (w>>1)*64 (A reused 2x).
struct CM {
    const _Float16* x; const half8_t* w1; const float* b1; const half8_t* gc; _Float16* sup;
};

__global__ __launch_bounds__(256) void convmix_kernel(CM P0, CM P1, int nblk0, int l) {
    __shared__ __align__(16) _Float16 Xs[136 * 68];
    int blk = blockIdx.x;
    CM P = (blk < nblk0) ? P0 : P1;
    if (blk >= nblk0) blk -= nblk0;
    int bn = blk >> 1, tc = blk & 1;
    int tid = threadIdx.x;
    stage_f16(P.x + (size_t)bn * HT, Xs, tc, tid);
    __syncthreads();

    int ln = tid & 63;
    int w = __builtin_amdgcn_readfirstlane(tid >> 6);
    int ln31 = ln & 31, kg = ln >> 5;
    int ob = (w & 1) * 32, tsub = (w >> 1) * 64;

    f32x16 acc[2];
#pragma unroll
    for (int ts = 0; ts < 2; ++ts)
#pragma unroll
        for (int r = 0; r < 16; ++r) acc[ts][r] = 0.f;

    const half8_t* wl = P.w1 + (size_t)l * (K_ * 8 * H_);
#pragma unroll
    for (int tap = 0; tap < K_; ++tap) {
#pragma unroll
        for (int ks = 0; ks < 4; ++ks) {
            int i8 = ks * 2 + kg;
            half8_t a = wl[(tap * 8 + i8) * H_ + ob + ln31];
#pragma unroll
            for (int ts = 0; ts < 2; ++ts) {
                half8_t bf = ld_b8(&Xs[(tsub + ts * 32 + ln31 + tap) * 68 + i8 * 8]);
                acc[ts] = __builtin_amdgcn_mfma_f32_32x32x16_f16(a, bf, acc[ts], 0, 0, 0);
            }
        }
    }
    __syncthreads();

    // conv1 epilogue: bias+relu -> mid rows Xs[4+t][o]
#pragma unroll
    for (int ts = 0; ts < 2; ++ts) {
        int row = 4 + tsub + ts * 32 + ln31;
#pragma unroll
        for (int rg = 0; rg < 4; ++rg) {
            int o0 = ob + rg * 8 + kg * 4;
            f32x4 bv = *(const f32x4*)(P.b1 + l * H_ + o0);
            half4_t hv;
#pragma unroll
            for (int j = 0; j < 4; ++j)
                hv[j] = (_Float16)fmaxf(acc[ts][rg * 4 + j] + bv[j], 0.f);
            *(half4_t*)(&Xs[row * 68 + o0]) = hv;
        }
    }
    __syncthreads();

    // channel mix (K=64)
    f32x16 acc2[2];
#pragma unroll
    for (int ts = 0; ts < 2; ++ts)
#pragma unroll
        for (int r = 0; r < 16; ++r) acc2[ts][r] = 0.f;
    const half8_t* gl = P.gc + (size_t)l * (8 * H_);
#pragma unroll
    for (int ks = 0; ks < 4; ++ks) {
        int i8 = ks * 2 + kg;
        half8_t a = gl[i8 * H_ + ob + ln31];
#pragma unroll
        for (int ts = 0; ts < 2; ++ts) {
            half8_t bf = ld_b8(&Xs[(4 + tsub + ts * 32 + ln31) * 68 + i8 * 8]);
            acc2[ts] = __builtin_amdgcn_mfma_f32_32x32x16_f16(a, bf, acc2[ts], 0, 0, 0);
        }
    }

    // store support f16 [bn][o][T]
    _Float16* sp = P.sup + (size_t)bn * HT + tc * 128;
#pragma unroll
    for (int ts = 0; ts < 2; ++ts) {
        int t = tsub + ts * 32 + ln31;
#pragma unroll
        for (int r = 0; r < 16; ++r) {
            int o = ob + (r & 3) + 8 * (r >> 2) + 4 * kg;
            sp[(size_t)o * T_ + t] = (_Float16)acc2[ts][r];
        }
    }
}

// ---------------- conv2(+bn)+residual : G f16 -> trunk f16; LAST: mean-pool -> feat ----------------
struct C2 {
    const _Float16* x; const half8_t* w2; const float* b2; _Float16* trunk; int N; int fbase;
};

template <bool LAST>
__global__ __launch_bounds__(256) void conv2_kernel(C2 P0, C2 P1, int nblk0, int l,
                                                    float* __restrict__ feat) {
    __shared__ __align__(16) _Float16 Xs[136 * 68];
    int blk = blockIdx.x;
    C2 P = (blk < nblk0) ? P0 : P1;
    if (blk >= nblk0) blk -= nblk0;
    int bn = blk >> 1, tc = blk & 1;
    int tid = threadIdx.x;
    stage_f16(P.x + (size_t)bn * HT, Xs, tc, tid);
    __syncthreads();

    int ln = tid & 63;
    int w = __builtin_amdgcn_readfirstlane(tid >> 6);
    int ln31 = ln & 31, kg = ln >> 5;
    int ob = (w & 1) * 32, tsub = (w >> 1) * 64;

    f32x16 acc[2];
#pragma unroll
    for (int ts = 0; ts < 2; ++ts)
#pragma unroll
        for (int r = 0; r < 16; ++r) acc[ts][r] = 0.f;

    const half8_t* wl = P.w2 + (size_t)l * (K_ * 8 * H_);
#pragma unroll
    for (int tap = 0; tap < K_; ++tap) {
#pragma unroll
        for (int ks = 0; ks < 4; ++ks) {
            int i8 = ks * 2 + kg;
            half8_t a = wl[(tap * 8 + i8) * H_ + ob + ln31];
#pragma unroll
            for (int ts = 0; ts < 2; ++ts) {
                half8_t bf = ld_b8(&Xs[(tsub + ts * 32 + ln31 + tap) * 68 + i8 * 8]);
                acc[ts] = __builtin_amdgcn_mfma_f32_32x32x16_f16(a, bf, acc[ts], 0, 0, 0);
            }
        }
    }

    const _Float16* resb = P.trunk + (size_t)bn * HT + tc * 128;
    if (!LAST) {
        _Float16* tob = P.trunk + (size_t)bn * HT + tc * 128;
#pragma unroll
        for (int ts = 0; ts < 2; ++ts) {
            int t = tsub + ts * 32 + ln31;
#pragma unroll
            for (int r = 0; r < 16; ++r) {
                int o = ob + (r & 3) + 8 * (r >> 2) + 4 * kg;
                float y = acc[ts][r] + P.b2[l * H_ + o] + (float)resb[(size_t)o * T_ + t];
                tob[(size_t)o * T_ + t] = (_Float16)y;
            }
        }
    } else {
        __syncthreads();   // Xs reads done; reuse as reduction scratch
        float* red = (float*)Xs;
        float sv[16];
#pragma unroll
        for (int r = 0; r < 16; ++r) {
            int o = ob + (r & 3) + 8 * (r >> 2) + 4 * kg;
            float bias = P.b2[l * H_ + o];
            float s = acc[0][r] + bias + (float)resb[(size_t)o * T_ + tsub + ln31]
                    + acc[1][r] + bias + (float)resb[(size_t)o * T_ + tsub + 32 + ln31];
#pragma unroll
            for (int off = 1; off < 32; off <<= 1) s += __shfl_xor(s, off);
            sv[r] = s;
        }
        if (ln31 == 0) {
#pragma unroll
            for (int r = 0; r < 16; ++r) {
                int o = ob + (r & 3) + 8 * (r >> 2) + 4 * kg;
                red[(w >> 1) * 64 + o] = sv[r];
            }
        }
        __syncthreads();
        if (tid < 64) {
            float s = red[tid] + red[64 + tid];
            int b = bn / P.N, n = bn % P.N;
            atomicAdd(&feat[(size_t)b * FEAT_DIM + P.fbase + n * H_ + tid], s * (1.f / 256.f));
        }
    }
}

// ---------------- adjmix MFMA: out = relu(adj @ sup + gb) ----------------
// Staging now NATURAL layout Ls[n][col] (pitch 132): conflict-free b128 writes;
// B-frag = 8x ds_read_u16 at row stride, lanes on consecutive col -> 2 lanes/bank (free).
template <int N, int MT, int KS>
__device__ __forceinline__ void adjmix_impl(const _Float16* __restrict__ sup,
                                            const half8_t* __restrict__ adjP,
                                            const float* __restrict__ gb,
                                            _Float16* __restrict__ out,
                                            int blk, int l, _Float16* Ls, int tid) {
    constexpr int KP = KS * 16;
    constexpr int PITCH = 132;          // 128 cols + 4 pad halves
    int b = blk >> 7, cb = blk & 127;
    int colbase = cb * 128;
    float gbv = gb[l * H_ + (cb >> 1)];

    for (int u = tid; u < KP * 16; u += 256) {
        int n = u >> 4, cs = u & 15;
        half8_t v;
        if (n < N) v = *(const half8_t*)(sup + (size_t)(b * N + n) * HT + colbase + cs * 8);
        else {
#pragma unroll
            for (int j = 0; j < 8; ++j) v[j] = (_Float16)0.f;
        }
        half4_t lo = __builtin_shufflevector(v, v, 0, 1, 2, 3);
        half4_t hi = __builtin_shufflevector(v, v, 4, 5, 6, 7);
        _Float16* dst = &Ls[n * PITCH + cs * 8];
        *(half4_t*)dst = lo;
        *(half4_t*)(dst + 4) = hi;
    }
    __syncthreads();

    int ln = tid & 63;
    int w = __builtin_amdgcn_readfirstlane(tid >> 6);
    int ln31 = ln & 31, kg = ln >> 5;
    int colL = w * 32 + ln31;

    f32x16 acc[MT];
#pragma unroll
    for (int mt = 0; mt < MT; ++mt)
#pragma unroll
        for (int r = 0; r < 16; ++r) acc[mt][r] = 0.f;

#pragma unroll
    for (int ks = 0; ks < KS; ++ks) {
        int n0 = ks * 16 + kg * 8;
        half8_t bf;
#pragma unroll
        for (int j = 0; j < 8; ++j) bf[j] = Ls[(n0 + j) * PITCH + colL];
#pragma unroll
        for (int mt = 0; mt < MT; ++mt) {
            half8_t af = adjP[(size_t)(mt * 32 + ln31) * (KP / 8) + ks * 2 + kg];
            acc[mt] = __builtin_amdgcn_mfma_f32_32x32x16_f16(af, bf, acc[mt], 0, 0, 0);
        }
    }

    int col = colbase + colL;
#pragma unroll
    for (int mt = 0; mt < MT; ++mt) {
#pragma unroll
        for (int r = 0; r < 16; ++r) {
            int m = mt * 32 + (r & 3) + 8 * (r >> 2) + 4 * kg;
            if (m < N)
                out[(size_t)(b * N + m) * HT + col] = (_Float16)fmaxf(acc[mt][r] + gbv, 0.f);
        }
    }
}

__global__ __launch_bounds__(256) void adjmix_kernel(
        const _Float16* __restrict__ supB, const half8_t* __restrict__ adjPB,
        const float* __restrict__ gbB, _Float16* __restrict__ outB,
        const _Float16* __restrict__ supF, const half8_t* __restrict__ adjPF,
        const float* __restrict__ gbF, _Float16* __restrict__ outF,
        int nblk0, int l) {
    __shared__ __align__(16) _Float16 Ls[80 * 132];
    int blk = blockIdx.x, tid = threadIdx.x;
    if (blk < nblk0)
        adjmix_impl<NB_, 1, 2>(supB, adjPB, gbB, outB, blk, l, Ls, tid);
    else
        adjmix_impl<NF_, 3, 5>(supF, adjPF, gbF, outF, blk - nblk0, l, Ls, tid);
}

// ---------------- fusion layer 1 (5504 -> 256), split-K ----------------
__global__ __launch_bounds__(256) void fus1_kernel(const float* __restrict__ feat,
                                                   const float* __restrict__ w1,
                                                   float* __restrict__ p1) {
    __shared__ float fv[128];
    int b = blockIdx.x / 43, ic = blockIdx.x % 43;
    int tid = threadIdx.x;
    if (tid < 128) fv[tid] = feat[(size_t)b * FEAT_DIM + ic * 128 + tid];
    __syncthreads();
    const float* wb = w1 + (size_t)(ic * 128) * 256 + tid;
    float acc = 0.f;
#pragma unroll 4
    for (int i = 0; i < 128; ++i)
        acc = fmaf(fv[i], wb[(size_t)i * 256], acc);
    atomicAdd(&p1[b * 256 + tid], acc);
}

// ---------------- fusion tail ----------------
__global__ __launch_bounds__(256) void fus_tail_kernel(const float* __restrict__ p1,
        const float* __restrict__ b1, const float* __restrict__ w2, const float* __restrict__ b2,
        const float* __restrict__ w3, const float* __restrict__ b3,
        const float* __restrict__ w4, const float* __restrict__ b4, float* __restrict__ out) {
    __shared__ float s1[256], s2[128], s3[64];
    int b = blockIdx.x, tid = threadIdx.x;
    s1[tid] = fmaxf(p1[b * 256 + tid] + b1[tid], 0.f);
    __syncthreads();
    if (tid < 128) {
        float acc = b2[tid];
        for (int i = 0; i < 256; ++i) acc = fmaf(s1[i], w2[i * 128 + tid], acc);
        s2[tid] = fmaxf(acc, 0.f);
    }
    __syncthreads();
    if (tid < 64) {
        float acc = b3[tid];
        for (int i = 0; i < 128; ++i) acc = fmaf(s2[i], w3[i * 64 + tid], acc);
        s3[tid] = fmaxf(acc, 0.f);
    }
    __syncthreads();
    if (tid < 5) {
        float acc = b4[tid];
        for (int i = 0; i < 64; ++i) acc = fmaf(s3[i], w4[i * 5 + tid], acc);
        out[b * 5 + tid] = acc;
    }
}

// ---------------- launch ----------------
extern "C" void kernel_launch(void* const* d_in, const int* in_sizes, int n_in,
                              void* d_out, int out_size, void* d_ws, size_t ws_size,
                              hipStream_t stream) {
    const float* body_kps = (const float*)d_in[0];
    const float* face_kps = (const float*)d_in[1];
    const float* head_pose = (const float*)d_in[2];
    const float* body_adj = (const float*)d_in[3];
    const float* face_adj = (const float*)d_in[4];
    const float* body_pw = (const float*)d_in[5];
    const float* body_pb = (const float*)d_in[6];
    const float* face_pw = (const float*)d_in[7];
    const float* face_pb = (const float*)d_in[8];
    const float* head_w = (const float*)d_in[9];
    const float* head_b = (const float*)d_in[10];
    const float* b_t1w = (const float*)d_in[11]; const float* b_t1b = (const float*)d_in[12];
    const float* b_g1  = (const float*)d_in[13]; const float* b_b1  = (const float*)d_in[14];
    const float* b_m1  = (const float*)d_in[15]; const float* b_v1  = (const float*)d_in[16];
    const float* b_gcw = (const float*)d_in[17]; const float* b_gcb = (const float*)d_in[18];
    const float* b_t2w = (const float*)d_in[19]; const float* b_t2b = (const float*)d_in[20];
    const float* b_g2  = (const float*)d_in[21]; const float* b_b2  = (const float*)d_in[22];
    const float* b_m2  = (const float*)d_in[23]; const float* b_v2  = (const float*)d_in[24];
    const float* f_t1w = (const float*)d_in[25]; const float* f_t1b = (const float*)d_in[26];
    const float* f_g1  = (const float*)d_in[27]; const float* f_b1  = (const float*)d_in[28];
    const float* f_m1  = (const float*)d_in[29]; const float* f_v1  = (const float*)d_in[30];
    const float* f_gcw = (const float*)d_in[31]; const float* f_gcb = (const float*)d_in[32];
    const float* f_t2w = (const float*)d_in[33]; const float* f_t2b = (const float*)d_in[34];
    const float* f_g2  = (const float*)d_in[35]; const float* f_b2  = (const float*)d_in[36];
    const float* f_m2  = (const float*)d_in[37]; const float* f_v2  = (const float*)d_in[38];
    const float* fus1_w = (const float*)d_in[39]; const float* fus1_b = (const float*)d_in[40];
    const float* fus2_w = (const float*)d_in[41]; const float* fus2_b = (const float*)d_in[42];
    const float* fus3_w = (const float*)d_in[43]; const float* fus3_b = (const float*)d_in[44];
    const float* fus4_w = (const float*)d_in[45]; const float* fus4_b = (const float*)d_in[46];

    float* ws = (float*)d_ws;
    _Float16* TrB = (_Float16*)(ws + OFF_TB);
    _Float16* TrF = (_Float16*)(ws + OFF_TF);
    _Float16* SupB = (_Float16*)(ws + OFF_SUPB);
    _Float16* SupF = (_Float16*)(ws + OFF_SUPF);
    _Float16* Gb = (_Float16*)(ws + OFF_GB);
    _Float16* Gf = (_Float16*)(ws + OFF_GF);
    _Float16* W3 = (_Float16*)(ws + OFF_W3);
    _Float16* W3b1 = W3;            _Float16* W3b2 = W3 + 110592;
    _Float16* W3f1 = W3 + 221184;   _Float16* W3f2 = W3 + 331776;
    _Float16* GW3 = (_Float16*)(ws + OFF_GW3);
    _Float16* GW3b = GW3;           _Float16* GW3f = GW3 + 12288;
    float* B2 = ws + OFF_B2;
    float* B2b1 = B2;        float* B2b2 = B2 + 192;
    float* B2f1 = B2 + 384;  float* B2f2 = B2 + 576;
    _Float16* adjPB = (_Float16*)(ws + OFF_ADJPB);
    _Float16* adjPF = (_Float16*)(ws + OFF_ADJPF);
    float* feat = ws + OFF_FEAT;
    float* p1 = ws + OFF_P1;
    float* out = (float*)d_out;

    // prep
    ConvPrepSet sb1{b_t1w, b_t1b, b_g1, b_b1, b_m1, b_v1};
    ConvPrepSet sb2{b_t2w, b_t2b, b_g2, b_b2, b_m2, b_v2};
    ConvPrepSet sf1{f_t1w, f_t1b, f_g1, f_b1, f_m1, f_v1};
    ConvPrepSet sf2{f_t2w, f_t2b, f_g2, f_b2, f_m2, f_v2};
    prep_convW_all<<<dim3(432, 4), 256, 0, stream>>>(sb1, sb2, sf1, sf2, W3, B2);
    prep_gcw_all<<<dim3(48, 2), 256, 0, stream>>>(b_gcw, f_gcw, GW3);
    prep_misc<<<214, 256, 0, stream>>>(body_adj, face_adj, adjPB, adjPF, p1, feat);

    const int nB = B_ * NB_;   // 136
    const int nF = B_ * NF_;   // 544
    proj_kernel<<<nB + nF + B_, 256, 0, stream>>>(body_kps, body_pw, body_pb, TrB,
                                                  face_kps, face_pw, face_pb, TrF,
                                                  head_pose, head_w, head_b, feat,
                                                  nB, nB + nF);

    CM cmb{TrB, (const half8_t*)W3b1, B2b1, (const half8_t*)GW3b, SupB};
    CM cmf{TrF, (const half8_t*)W3f1, B2f1, (const half8_t*)GW3f, SupF};
    C2 c2b{Gb, (const half8_t*)W3b2, B2b2, TrB, NB_, 0};
    C2 c2f{Gf, (const half8_t*)W3f2, B2f2, TrF, NF_, NB_ * H_};

    const int gc = (nB + nF) * 2;   // 1360
    const int n0 = nB * 2;          // 272
    const int ga = B_ * 128;        // 1024 per stream

    for (int l = 0; l < L_; ++l) {
        convmix_kernel<<<gc, 256, 0, stream>>>(cmb, cmf, n0, l);
        adjmix_kernel<<<2 * ga, 256, 0, stream>>>(SupB, (const half8_t*)adjPB, b_gcb, Gb,
                                                  SupF, (const half8_t*)adjPF, f_gcb, Gf, ga, l);
        if (l < L_ - 1)
            conv2_kernel<false><<<gc, 256, 0, stream>>>(c2b, c2f, n0, l, feat);
        else
            conv2_kernel<true><<<gc, 256, 0, stream>>>(c2b, c2f, n0, l, feat);
    }

    fus1_kernel<<<B_ * 43, 256, 0, stream>>>(feat, fus1_w, p1);
    fus_tail_kernel<<<B_, 256, 0, stream>>>(p1, fus1_b, fus2_w, fus2_b, fus3_w, fus3_b,
                                            fus4_w, fus4_b, out);
}

// Round 14
// 394.993 us; speedup vs baseline: 1.0551x; 1.0179x over previous
//
#include <hip/hip_runtime.h>

// ---------------- problem constants ----------------
constexpr int B_ = 8, T_ = 256, H_ = 64, L_ = 3, NB_ = 17, NF_ = 68, HP_ = 6, K_ = 9;
constexpr int FEAT_DIM = NB_ * H_ + NF_ * H_ + H_;   // 5504
constexpr int HT = H_ * T_;                          // 16384 per (b,n)

typedef _Float16 half4_t __attribute__((ext_vector_type(4)));
typedef _Float16 half8_t __attribute__((ext_vector_type(8)));
typedef float f32x16 __attribute__((ext_vector_type(16)));
typedef float f32x4 __attribute__((ext_vector_type(4)));

// ---------------- workspace layout (float units); activations f16 [bn][o][T] ----------------
constexpr size_t SZ_AB = (size_t)B_ * NB_ * HT;
constexpr size_t SZ_AF = (size_t)B_ * NF_ * HT;
constexpr size_t OFF_TB   = 0;
constexpr size_t OFF_TF   = OFF_TB + SZ_AB / 2;
constexpr size_t OFF_SUPB = OFF_TF + SZ_AF / 2;
constexpr size_t OFF_SUPF = OFF_SUPB + SZ_AB / 2;
constexpr size_t OFF_GB   = OFF_SUPF + SZ_AF / 2;
constexpr size_t OFF_GF   = OFF_GB + SZ_AB / 2;
constexpr size_t OFF_W3   = OFF_GF + SZ_AF / 2;      // 4 conv sets x 110592 f16
constexpr size_t OFF_GW3  = OFF_W3 + 4 * 55296;      // 2 x 12288 f16
constexpr size_t OFF_B2   = OFF_GW3 + 2 * 6144;      // 4 x 192 f32
constexpr size_t OFF_ADJPB= OFF_B2 + 768;            // 32x32 f16
constexpr size_t OFF_ADJPF= OFF_ADJPB + 512;         // 96x80 f16
constexpr size_t OFF_FEAT = OFF_ADJPF + 3840;        // 8x5504 f32
constexpr size_t OFF_P1   = OFF_FEAT + (size_t)B_ * FEAT_DIM;

// ---------------- prep: fold BN into conv W -> f16 [l][tap][i8][o][j], 4 sets ----------------
struct ConvPrepSet { const float *w, *tb, *g, *bb, *m, *v; };

__global__ __launch_bounds__(256) void prep_convW_all(ConvPrepSet s0, ConvPrepSet s1,
                                                      ConvPrepSet s2, ConvPrepSet s3,
                                                      _Float16* __restrict__ w3,
                                                      float* __restrict__ b2) {
    int set = blockIdx.y;
    ConvPrepSet s = (set == 0) ? s0 : (set == 1) ? s1 : (set == 2) ? s2 : s3;
    int idx = blockIdx.x * 256 + threadIdx.x;           // < 110592
    int k = idx % K_; int r = idx / K_;
    int i = r % H_; r /= H_;
    int o = r % H_; int l = r / H_;
    float sc = s.g[l * H_ + o] * rsqrtf(s.v[l * H_ + o] + 1e-5f);
    w3[(size_t)set * 110592 + ((((l * K_ + k) * 8 + (i >> 3)) * H_ + o) * 8) + (i & 7)]
        = (_Float16)(s.w[idx] * sc);
    if (i == 0 && k == 0)
        b2[set * 192 + l * H_ + o] =
            s.tb[l * H_ + o] * sc + s.bb[l * H_ + o] - s.m[l * H_ + o] * sc;
}

__global__ __launch_bounds__(256) void prep_gcw_all(const float* __restrict__ g0,
                                                    const float* __restrict__ g1,
                                                    _Float16* __restrict__ w3) {
    int set = blockIdx.y;
    const float* gw = set ? g1 : g0;
    int idx = blockIdx.x * 256 + threadIdx.x;           // < 12288
    int o = idx % H_; int r = idx / H_;
    int c = r % H_; int l = r / H_;
    w3[(size_t)set * 12288 + (((l * 8 + (c >> 3)) * H_ + o) * 8) + (c & 7)] = (_Float16)gw[idx];
}

// padded f16 adj ([m][Kpad] A-layout) + zero p1 + zero feat
__global__ __launch_bounds__(256) void prep_misc(const float* __restrict__ adjB,
                                                 const float* __restrict__ adjF,
                                                 _Float16* __restrict__ pB,
                                                 _Float16* __restrict__ pF,
                                                 float* __restrict__ p1,
                                                 float* __restrict__ feat) {
    int idx = blockIdx.x * 256 + threadIdx.x;
    if (idx < 1024) {
        int m = idx >> 5, k = idx & 31;
        pB[idx] = (m < NB_ && k < NB_) ? (_Float16)adjB[m * NB_ + k] : (_Float16)0.f;
    } else if (idx < 8704) {
        int j = idx - 1024;
        int m = j / 80, k = j % 80;
        pF[j] = (m < NF_ && k < NF_) ? (_Float16)adjF[m * NF_ + k] : (_Float16)0.f;
    } else if (idx < 10752) {
        p1[idx - 8704] = 0.f;
    } else if (idx < 10752 + B_ * FEAT_DIM) {
        feat[idx - 10752] = 0.f;
    }
}

// ---------------- projection -> trunk f16 [bn][o][T] ; tail blocks do head stream ----------------
__global__ __launch_bounds__(256) void proj_kernel(const float* __restrict__ kpsB,
                                                   const float* __restrict__ pwB,
                                                   const float* __restrict__ pbB,
                                                   _Float16* __restrict__ outB,
                                                   const float* __restrict__ kpsF,
                                                   const float* __restrict__ pwF,
                                                   const float* __restrict__ pbF,
                                                   _Float16* __restrict__ outF,
                                                   const float* __restrict__ hx,
                                                   const float* __restrict__ hw,
                                                   const float* __restrict__ hb,
                                                   float* __restrict__ feat,
                                                   int nblk0, int nblk1) {
    int blk = blockIdx.x;
    if (blk >= nblk1) {             // head stream: 8 blocks, 64 lanes used
        int b = blk - nblk1;
        int c = threadIdx.x;
        if (c >= 64) return;
        float w0 = hw[c], w1 = hw[64 + c], w2 = hw[128 + c],
              w3 = hw[192 + c], w4 = hw[256 + c], w5 = hw[320 + c];
        float bias = hb[c];
        float acc = 0.f;
        for (int t = 0; t < T_; ++t) {
            const float* xr = hx + ((size_t)b * T_ + t) * HP_;
            float s = fmaf(xr[0], w0, fmaf(xr[1], w1, fmaf(xr[2], w2,
                      fmaf(xr[3], w3, fmaf(xr[4], w4, fmaf(xr[5], w5, bias))))));
            acc += fmaxf(s, 0.f);
        }
        feat[(size_t)b * FEAT_DIM + NB_ * H_ + NF_ * H_ + c] = acc * (1.f / 256.f);
        return;
    }
    const float *kps, *pw, *pb; _Float16* out; int N, bn;
    if (blk < nblk0) { kps = kpsB; pw = pwB; pb = pbB; out = outB; N = NB_; bn = blk; }
    else { kps = kpsF; pw = pwF; pb = pbF; out = outF; N = NF_; bn = blk - nblk0; }
    int b = bn / N, n = bn % N;
    int t = threadIdx.x;
    float x0 = kps[((size_t)b * T_ + t) * (N * 2) + n * 2 + 0];
    float x1 = kps[((size_t)b * T_ + t) * (N * 2) + n * 2 + 1];
    _Float16* ob = out + (size_t)bn * HT + t;
#pragma unroll 8
    for (int c = 0; c < H_; ++c)
        ob[(size_t)c * T_] = (_Float16)fmaf(x0, pw[c], fmaf(x1, pw[H_ + c], pb[c]));
}

__device__ __forceinline__ half8_t ld_b8(const _Float16* p) {
    half4_t lo = *(const half4_t*)p;
    half4_t hi = *(const half4_t*)(p + 4);
    return __builtin_shufflevector(lo, hi, 0, 1, 2, 3, 4, 5, 6, 7);
}

// stage f16 [c][T] -> Xs[t_local+4][c], pitch 68 (gather: 8 coalesced u16 loads -> 2 b64 writes)
__device__ __forceinline__ void stage_f16(const _Float16* __restrict__ xb,
                                          _Float16* __restrict__ Xs, int tc, int tid) {
    for (int u = tid; u < 8 * 136; u += 256) {
        int oct = u / 136;
        int row = u - oct * 136;
        int t = tc * 128 + row - 4;
        _Float16 v[8];
        if (t >= 0 && t < T_) {
            const _Float16* xr = xb + (size_t)(oct * 8) * T_ + t;
#pragma unroll
            for (int j = 0; j < 8; ++j) v[j] = xr[(size_t)j * T_];
        } else {
#pragma unroll
            for (int j = 0; j < 8; ++j) v[j] = (_Float16)0.f;
        }
        _Float16* dst = &Xs[row * 68 + oct * 8];
        half4_t lo, hi;
#pragma unroll
        for (int j = 0; j < 4; ++j) { lo[j] = v[j]; hi[j] = v[4 + j]; }
        *(half4_t*)dst = lo;
        *(half4_t*)(dst + 4) = hi;
    }
}

// ---------------- fused conv1(+bn+relu)+channel-mix : trunk f16 -> support f16 ----------------
// block = (bn, t-chunk 128), 4 waves; wave w: t-tile w*32, BOTH o-tiles.
// Per K-step: 2 A-loads + 1 B-LDS-read -> 2 MFMA (512 B LDS/MFMA).
struct CM {
    const _Float16* x; const half8_t* w1; const float* b1; const half8_t* gc; _Float16* sup;
};

__global__ __launch_bounds__(256) void convmix_kernel(CM P0, CM P1, int nblk0, int l) {
    __shared__ __align__(16) _Float16 Xs[136 * 68];
    int blk = blockIdx.x;
    CM P = (blk < nblk0) ? P0 : P1;
    if (blk >= nblk0) blk -= nblk0;
    int bn = blk >> 1, tc = blk & 1;
    int tid = threadIdx.x;
    stage_f16(P.x + (size_t)bn * HT, Xs, tc, tid);
    __syncthreads();

    int ln = tid & 63;
    int w = __builtin_amdgcn_readfirstlane(tid >> 6);
    int ln31 = ln & 31, kg = ln >> 5;
    int tsub = w * 32;

    f32x16 acc[2];   // [mt]
#pragma unroll
    for (int mt = 0; mt < 2; ++mt)
#pragma unroll
        for (int r = 0; r < 16; ++r) acc[mt][r] = 0.f;

    const half8_t* wl = P.w1 + (size_t)l * (K_ * 8 * H_);
    const _Float16* xrow0 = Xs + (size_t)(tsub + ln31) * 68;
#pragma unroll
    for (int tap = 0; tap < K_; ++tap) {
#pragma unroll
        for (int ks = 0; ks < 4; ++ks) {
            int i8 = ks * 2 + kg;
            half8_t a0 = wl[(tap * 8 + i8) * H_ + ln31];
            half8_t a1 = wl[(tap * 8 + i8) * H_ + 32 + ln31];
            half8_t bf = ld_b8(xrow0 + tap * 68 + i8 * 8);
            acc[0] = __builtin_amdgcn_mfma_f32_32x32x16_f16(a0, bf, acc[0], 0, 0, 0);
            acc[1] = __builtin_amdgcn_mfma_f32_32x32x16_f16(a1, bf, acc[1], 0, 0, 0);
        }
    }
    __syncthreads();

    // conv1 epilogue: bias+relu -> mid row Xs[4+t][o] (both o-tiles)
    {
        _Float16* mrow = Xs + (size_t)(4 + tsub + ln31) * 68;
#pragma unroll
        for (int mt = 0; mt < 2; ++mt) {
#pragma unroll
            for (int rg = 0; rg < 4; ++rg) {
                int o0 = mt * 32 + rg * 8 + kg * 4;
                f32x4 bv = *(const f32x4*)(P.b1 + l * H_ + o0);
                half4_t hv;
#pragma unroll
                for (int j = 0; j < 4; ++j)
                    hv[j] = (_Float16)fmaxf(acc[mt][rg * 4 + j] + bv[j], 0.f);
                *(half4_t*)(mrow + o0) = hv;
            }
        }
    }
    __syncthreads();

    // channel mix (K=64)
    f32x16 acc2[2];
#pragma unroll
    for (int mt = 0; mt < 2; ++mt)
#pragma unroll
        for (int r = 0; r < 16; ++r) acc2[mt][r] = 0.f;
    const half8_t* gl = P.gc + (size_t)l * (8 * H_);
    const _Float16* mrow = Xs + (size_t)(4 + tsub + ln31) * 68;
#pragma unroll
    for (int ks = 0; ks < 4; ++ks) {
        int i8 = ks * 2 + kg;
        half8_t a0 = gl[i8 * H_ + ln31];
        half8_t a1 = gl[i8 * H_ + 32 + ln31];
        half8_t bf = ld_b8(mrow + i8 * 8);
        acc2[0] = __builtin_amdgcn_mfma_f32_32x32x16_f16(a0, bf, acc2[0], 0, 0, 0);
        acc2[1] = __builtin_amdgcn_mfma_f32_32x32x16_f16(a1, bf, acc2[1], 0, 0, 0);
    }

    // store support f16 [bn][o][T]
    int t = tc * 128 + tsub + ln31;
    _Float16* sp = P.sup + (size_t)bn * HT + t;
#pragma unroll
    for (int mt = 0; mt < 2; ++mt) {
#pragma unroll
        for (int r = 0; r < 16; ++r) {
            int o = mt * 32 + (r & 3) + 8 * (r >> 2) + 4 * kg;
            sp[(size_t)o * T_] = (_Float16)acc2[mt][r];
        }
    }
}

// ---------------- conv2(+bn)+residual : G f16 -> trunk f16; LAST: mean-pool -> feat ----------------
struct C2 {
    const _Float16* x; const half8_t* w2; const float* b2; _Float16* trunk; int N; int fbase;
};

template <bool LAST>
__global__ __launch_bounds__(256) void conv2_kernel(C2 P0, C2 P1, int nblk0, int l,
                                                    float* __restrict__ feat) {
    __shared__ __align__(16) _Float16 Xs[136 * 68];
    int blk = blockIdx.x;
    C2 P = (blk < nblk0) ? P0 : P1;
    if (blk >= nblk0) blk -= nblk0;
    int bn = blk >> 1, tc = blk & 1;
    int tid = threadIdx.x;
    stage_f16(P.x + (size_t)bn * HT, Xs, tc, tid);
    __syncthreads();

    int ln = tid & 63;
    int w = __builtin_amdgcn_readfirstlane(tid >> 6);
    int ln31 = ln & 31, kg = ln >> 5;
    int tsub = w * 32;

    f32x16 acc[2];
#pragma unroll
    for (int mt = 0; mt < 2; ++mt)
#pragma unroll
        for (int r = 0; r < 16; ++r) acc[mt][r] = 0.f;

    const half8_t* wl = P.w2 + (size_t)l * (K_ * 8 * H_);
    const _Float16* xrow0 = Xs + (size_t)(tsub + ln31) * 68;
#pragma unroll
    for (int tap = 0; tap < K_; ++tap) {
#pragma unroll
        for (int ks = 0; ks < 4; ++ks) {
            int i8 = ks * 2 + kg;
            half8_t a0 = wl[(tap * 8 + i8) * H_ + ln31];
            half8_t a1 = wl[(tap * 8 + i8) * H_ + 32 + ln31];
            half8_t bf = ld_b8(xrow0 + tap * 68 + i8 * 8);
            acc[0] = __builtin_amdgcn_mfma_f32_32x32x16_f16(a0, bf, acc[0], 0, 0, 0);
            acc[1] = __builtin_amdgcn_mfma_f32_32x32x16_f16(a1, bf, acc[1], 0, 0, 0);
        }
    }

    int t = tc * 128 + tsub + ln31;
    const _Float16* resb = P.trunk + (size_t)bn * HT + t;
    if (!LAST) {
        _Float16* tob = P.trunk + (size_t)bn * HT + t;
#pragma unroll
        for (int mt = 0; mt < 2; ++mt) {
#pragma unroll
            for (int r = 0; r < 16; ++r) {
                int o = mt * 32 + (r & 3) + 8 * (r >> 2) + 4 * kg;
                float y = acc[mt][r] + P.b2[l * H_ + o] + (float)resb[(size_t)o * T_];
                tob[(size_t)o * T_] = (_Float16)y;
            }
        }
    } else {
        __syncthreads();   // Xs reads done; reuse as reduction scratch
        float* red = (float*)Xs;
        float sv[2][16];
#pragma unroll
        for (int mt = 0; mt < 2; ++mt) {
#pragma unroll
            for (int r = 0; r < 16; ++r) {
                int o = mt * 32 + (r & 3) + 8 * (r >> 2) + 4 * kg;
                float s = acc[mt][r] + P.b2[l * H_ + o] + (float)resb[(size_t)o * T_];
#pragma unroll
                for (int off = 1; off < 32; off <<= 1) s += __shfl_xor(s, off);
                sv[mt][r] = s;
            }
        }
        if (ln31 == 0) {
#pragma unroll
            for (int mt = 0; mt < 2; ++mt)
#pragma unroll
                for (int r = 0; r < 16; ++r) {
                    int o = mt * 32 + (r & 3) + 8 * (r >> 2) + 4 * kg;
                    red[w * 64 + o] = sv[mt][r];
                }
        }
        __syncthreads();
        if (tid < 64) {
            float s = red[tid] + red[64 + tid] + red[128 + tid] + red[192 + tid];
            int b = bn / P.N, n = bn % P.N;
            atomicAdd(&feat[(size_t)b * FEAT_DIM + P.fbase + n * H_ + tid], s * (1.f / 256.f));
        }
    }
}

// ---------------- adjmix MFMA (round-11 version): out = relu(adj @ sup + gb) ----------------
template <int N, int MT, int KS>
__device__ __forceinline__ void adjmix_impl(const _Float16* __restrict__ sup,
                                            const half8_t* __restrict__ adjP,
                                            const float* __restrict__ gb,
                                            _Float16* __restrict__ out,
                                            int blk, int l, _Float16* Ls, int tid) {
    constexpr int KP = KS * 16;
    constexpr int PITCH = KP + 4;
    int b = blk >> 7, cb = blk & 127;
    int colbase = cb * 128;
    float gbv = gb[l * H_ + (cb >> 1)];

    for (int u = tid; u < KP * 16; u += 256) {
        int n = u >> 4, cs = u & 15;
        half8_t v;
        if (n < N) v = *(const half8_t*)(sup + (size_t)(b * N + n) * HT + colbase + cs * 8);
        else {
#pragma unroll
            for (int j = 0; j < 8; ++j) v[j] = (_Float16)0.f;
        }
#pragma unroll
        for (int j = 0; j < 8; ++j) Ls[(cs * 8 + j) * PITCH + n] = v[j];
    }
    __syncthreads();

    int ln = tid & 63;
    int w = __builtin_amdgcn_readfirstlane(tid >> 6);
    int ln31 = ln & 31, kg = ln >> 5;
    int colL = w * 32 + ln31;

    f32x16 acc[MT];
#pragma unroll
    for (int mt = 0; mt < MT; ++mt)
#pragma unroll
        for (int r = 0; r < 16; ++r) acc[mt][r] = 0.f;

#pragma unroll
    for (int ks = 0; ks < KS; ++ks) {
        half8_t bf = ld_b8(&Ls[colL * PITCH + ks * 16 + kg * 8]);
#pragma unroll
        for (int mt = 0; mt < MT; ++mt) {
            half8_t af = adjP[(size_t)(mt * 32 + ln31) * (KP / 8) + ks * 2 + kg];
            acc[mt] = __builtin_amdgcn_mfma_f32_32x32x16_f16(af, bf, acc[mt], 0, 0, 0);
        }
    }

    int col = colbase + colL;
#pragma unroll
    for (int mt = 0; mt < MT; ++mt) {
#pragma unroll
        for (int r = 0; r < 16; ++r) {
            int m = mt * 32 + (r & 3) + 8 * (r >> 2) + 4 * kg;
            if (m < N)
                out[(size_t)(b * N + m) * HT + col] = (_Float16)fmaxf(acc[mt][r] + gbv, 0.f);
        }
    }
}

__global__ __launch_bounds__(256) void adjmix_kernel(
        const _Float16* __restrict__ supB, const half8_t* __restrict__ adjPB,
        const float* __restrict__ gbB, _Float16* __restrict__ outB,
        const _Float16* __restrict__ supF, const half8_t* __restrict__ adjPF,
        const float* __restrict__ gbF, _Float16* __restrict__ outF,
        int nblk0, int l) {
    __shared__ __align__(16) _Float16 Ls[128 * 84];
    int blk = blockIdx.x, tid = threadIdx.x;
    if (blk < nblk0)
        adjmix_impl<NB_, 1, 2>(supB, adjPB, gbB, outB, blk, l, Ls, tid);
    else
        adjmix_impl<NF_, 3, 5>(supF, adjPF, gbF, outF, blk - nblk0, l, Ls, tid);
}

// ---------------- fusion layer 1 (5504 -> 256), split-K ----------------
__global__ __launch_bounds__(256) void fus1_kernel(const float* __restrict__ feat,
                                                   const float* __restrict__ w1,
                                                   float* __restrict__ p1) {
    __shared__ float fv[128];
    int b = blockIdx.x / 43, ic = blockIdx.x % 43;
    int tid = threadIdx.x;
    if (tid < 128) fv[tid] = feat[(size_t)b * FEAT_DIM + ic * 128 + tid];
    __syncthreads();
    const float* wb = w1 + (size_t)(ic * 128) * 256 + tid;
    float acc = 0.f;
#pragma unroll 4
    for (int i = 0; i < 128; ++i)
        acc = fmaf(fv[i], wb[(size_t)i * 256], acc);
    atomicAdd(&p1[b * 256 + tid], acc);
}

// ---------------- fusion tail ----------------
__global__ __launch_bounds__(256) void fus_tail_kernel(const float* __restrict__ p1,
        const float* __restrict__ b1, const float* __restrict__ w2, const float* __restrict__ b2,
        const float* __restrict__ w3, const float* __restrict__ b3,
        const float* __restrict__ w4, const float* __restrict__ b4, float* __restrict__ out) {
    __shared__ float s1[256], s2[128], s3[64];
    int b = blockIdx.x, tid = threadIdx.x;
    s1[tid] = fmaxf(p1[b * 256 + tid] + b1[tid], 0.f);
    __syncthreads();
    if (tid < 128) {
        float acc = b2[tid];
        for (int i = 0; i < 256; ++i) acc = fmaf(s1[i], w2[i * 128 + tid], acc);
        s2[tid] = fmaxf(acc, 0.f);
    }
    __syncthreads();
    if (tid < 64) {
        float acc = b3[tid];
        for (int i = 0; i < 128; ++i) acc = fmaf(s2[i], w3[i * 64 + tid], acc);
        s3[tid] = fmaxf(acc, 0.f);
    }
    __syncthreads();
    if (tid < 5) {
        float acc = b4[tid];
        for (int i = 0; i < 64; ++i) acc = fmaf(s3[i], w4[i * 5 + tid], acc);
        out[b * 5 + tid] = acc;
    }
}

// ---------------- launch ----------------
extern "C" void kernel_launch(void* const* d_in, const int* in_sizes, int n_in,
                              void* d_out, int out_size, void* d_ws, size_t ws_size,
                              hipStream_t stream) {
    const float* body_kps = (const float*)d_in[0];
    const float* face_kps = (const float*)d_in[1];
    const float* head_pose = (const float*)d_in[2];
    const float* body_adj = (const float*)d_in[3];
    const float* face_adj = (const float*)d_in[4];
    const float* body_pw = (const float*)d_in[5];
    const float* body_pb = (const float*)d_in[6];
    const float* face_pw = (const float*)d_in[7];
    const float* face_pb = (const float*)d_in[8];
    const float* head_w = (const float*)d_in[9];
    const float* head_b = (const float*)d_in[10];
    const float* b_t1w = (const float*)d_in[11]; const float* b_t1b = (const float*)d_in[12];
    const float* b_g1  = (const float*)d_in[13]; const float* b_b1  = (const float*)d_in[14];
    const float* b_m1  = (const float*)d_in[15]; const float* b_v1  = (const float*)d_in[16];
    const float* b_gcw = (const float*)d_in[17]; const float* b_gcb = (const float*)d_in[18];
    const float* b_t2w = (const float*)d_in[19]; const float* b_t2b = (const float*)d_in[20];
    const float* b_g2  = (const float*)d_in[21]; const float* b_b2  = (const float*)d_in[22];
    const float* b_m2  = (const float*)d_in[23]; const float* b_v2  = (const float*)d_in[24];
    const float* f_t1w = (const float*)d_in[25]; const float* f_t1b = (const float*)d_in[26];
    const float* f_g1  = (const float*)d_in[27]; const float* f_b1  = (const float*)d_in[28];
    const float* f_m1  = (const float*)d_in[29]; const float* f_v1  = (const float*)d_in[30];
    const float* f_gcw = (const float*)d_in[31]; const float* f_gcb = (const float*)d_in[32];
    const float* f_t2w = (const float*)d_in[33]; const float* f_t2b = (const float*)d_in[34];
    const float* f_g2  = (const float*)d_in[35]; const float* f_b2  = (const float*)d_in[36];
    const float* f_m2  = (const float*)d_in[37]; const float* f_v2  = (const float*)d_in[38];
    const float* fus1_w = (const float*)d_in[39]; const float* fus1_b = (const float*)d_in[40];
    const float* fus2_w = (const float*)d_in[41]; const float* fus2_b = (const float*)d_in[42];
    const float* fus3_w = (const float*)d_in[43]; const float* fus3_b = (const float*)d_in[44];
    const float* fus4_w = (const float*)d_in[45]; const float* fus4_b = (const float*)d_in[46];

    float* ws = (float*)d_ws;
    _Float16* TrB = (_Float16*)(ws + OFF_TB);
    _Float16* TrF = (_Float16*)(ws + OFF_TF);
    _Float16* SupB = (_Float16*)(ws + OFF_SUPB);
    _Float16* SupF = (_Float16*)(ws + OFF_SUPF);
    _Float16* Gb = (_Float16*)(ws + OFF_GB);
    _Float16* Gf = (_Float16*)(ws + OFF_GF);
    _Float16* W3 = (_Float16*)(ws + OFF_W3);
    _Float16* W3b1 = W3;            _Float16* W3b2 = W3 + 110592;
    _Float16* W3f1 = W3 + 221184;   _Float16* W3f2 = W3 + 331776;
    _Float16* GW3 = (_Float16*)(ws + OFF_GW3);
    _Float16* GW3b = GW3;           _Float16* GW3f = GW3 + 12288;
    float* B2 = ws + OFF_B2;
    float* B2b1 = B2;        float* B2b2 = B2 + 192;
    float* B2f1 = B2 + 384;  float* B2f2 = B2 + 576;
    _Float16* adjPB = (_Float16*)(ws + OFF_ADJPB);
    _Float16* adjPF = (_Float16*)(ws + OFF_ADJPF);
    float* feat = ws + OFF_FEAT;
    float* p1 = ws + OFF_P1;
    float* out = (float*)d_out;

    // prep
    ConvPrepSet sb1{b_t1w, b_t1b, b_g1, b_b1, b_m1, b_v1};
    ConvPrepSet sb2{b_t2w, b_t2b, b_g2, b_b2, b_m2, b_v2};
    ConvPrepSet sf1{f_t1w, f_t1b, f_g1, f_b1, f_m1, f_v1};
    ConvPrepSet sf2{f_t2w, f_t2b, f_g2, f_b2, f_m2, f_v2};
    prep_convW_all<<<dim3(432, 4), 256, 0, stream>>>(sb1, sb2, sf1, sf2, W3, B2);
    prep_gcw_all<<<dim3(48, 2), 256, 0, stream>>>(b_gcw, f_gcw, GW3);
    prep_misc<<<214, 256, 0, stream>>>(body_adj, face_adj, adjPB, adjPF, p1, feat);

    const int nB = B_ * NB_;   // 136
    const int nF = B_ * NF_;   // 544
    proj_kernel<<<nB + nF + B_, 256, 0, stream>>>(body_kps, body_pw, body_pb, TrB,
                                                  face_kps, face_pw, face_pb, TrF,
                                                  head_pose, head_w, head_b, feat,
                                                  nB, nB + nF);

    CM cmb{TrB, (const half8_t*)W3b1, B2b1, (const half8_t*)GW3b, SupB};
    CM cmf{TrF, (const half8_t*)W3f1, B2f1, (const half8_t*)GW3f, SupF};
    C2 c2b{Gb, (const half8_t*)W3b2, B2b2, TrB, NB_, 0};
    C2 c2f{Gf, (const half8_t*)W3f2, B2f2, TrF, NF_, NB_ * H_};

    const int gc = (nB + nF) * 2;   // 1360
    const int n0 = nB * 2;          // 272
    const int ga = B_ * 128;        // 1024 per stream

    for (int l = 0; l < L_; ++l) {
        convmix_kernel<<<gc, 256, 0, stream>>>(cmb, cmf, n0, l);
        adjmix_kernel<<<2 * ga, 256, 0, stream>>>(SupB, (const half8_t*)adjPB, b_gcb, Gb,
                                                  SupF, (const half8_t*)adjPF, f_gcb, Gf, ga, l);
        if (l < L_ - 1)
            conv2_kernel<false><<<gc, 256, 0, stream>>>(c2b, c2f, n0, l, feat);
        else
            conv2_kernel<true><<<gc, 256, 0, stream>>>(c2b, c2f, n0, l, feat);
    }

    fus1_kernel<<<B_ * 43, 256, 0, stream>>>(feat, fus1_w, p1);
    fus_tail_kernel<<<B_, 256, 0, stream>>>(p1, fus1_b, fus2_w, fus2_b, fus3_w, fus3_b,
                                            fus4_w, fus4_b, out);
}